// Round 1
// baseline (1271.504 us; speedup 1.0000x reference)
//
#include <hip/hip_runtime.h>

// ---------------------------------------------------------------------------
// QCNN classifier: whole circuit == fixed 1024x1024 unitary U(weights).
// out[b,k] = sum_s sign_k(s) |(U x_b)_s|^2 / ||x_b||^2
// Pipeline: build 27 composite 4x4 gates -> simulate U columns in LDS ->
// fp32 GEMM X(16384x1024) @ [ReU^T | ImU^T](1024x2048) with fused
// signed-square reduction -> divide by row norms.
// ---------------------------------------------------------------------------

struct Gate { int p1, p2; float2 m[16]; };   // p1 = bitpos of high gate index bit

__device__ inline float2 cmul(float2 a, float2 b) {
    return make_float2(a.x * b.x - a.y * b.y, a.x * b.y + a.y * b.x);
}
__device__ inline float2 cadd(float2 a, float2 b) {
    return make_float2(a.x + b.x, a.y + b.y);
}

struct M2 { float2 m[4]; };
struct M4 { float2 m[16]; };

__device__ M4 m4_zero() {
    M4 C;
    for (int i = 0; i < 16; i++) C.m[i] = make_float2(0.f, 0.f);
    return C;
}

__device__ M4 mul4(const M4& A, const M4& B) {
    M4 C;
    for (int i = 0; i < 4; i++)
        for (int j = 0; j < 4; j++) {
            float2 s = make_float2(0.f, 0.f);
            for (int k = 0; k < 4; k++) s = cadd(s, cmul(A.m[i * 4 + k], B.m[k * 4 + j]));
            C.m[i * 4 + j] = s;
        }
    return C;
}

// U acting on high qubit of (a,b) pair: U (x) I
__device__ M4 kronA(const M2& U) {
    M4 C = m4_zero();
    for (int a2 = 0; a2 < 2; a2++)
        for (int a = 0; a < 2; a++)
            for (int b = 0; b < 2; b++)
                C.m[(2 * a2 + b) * 4 + (2 * a + b)] = U.m[a2 * 2 + a];
    return C;
}
// U acting on low qubit: I (x) U
__device__ M4 kronB(const M2& U) {
    M4 C = m4_zero();
    for (int a = 0; a < 2; a++)
        for (int b2 = 0; b2 < 2; b2++)
            for (int b = 0; b < 2; b++)
                C.m[(2 * a + b2) * 4 + (2 * a + b)] = U.m[b2 * 2 + b];
    return C;
}

__device__ M2 m2_u3(float t, float p, float d) {
    float c = cosf(0.5f * t), s = sinf(0.5f * t);
    float2 ep = make_float2(cosf(p), sinf(p));
    float2 ed = make_float2(cosf(d), sinf(d));
    M2 U;
    U.m[0] = make_float2(c, 0.f);
    U.m[1] = make_float2(-ed.x * s, -ed.y * s);
    U.m[2] = make_float2(ep.x * s, ep.y * s);
    float2 epd = cmul(ep, ed);
    U.m[3] = make_float2(epd.x * c, epd.y * c);
    return U;
}
__device__ M2 m2_ry(float t) {
    float c = cosf(0.5f * t), s = sinf(0.5f * t);
    M2 U;
    U.m[0] = make_float2(c, 0.f);  U.m[1] = make_float2(-s, 0.f);
    U.m[2] = make_float2(s, 0.f);  U.m[3] = make_float2(c, 0.f);
    return U;
}
__device__ M2 m2_rz(float t) {
    float c = cosf(0.5f * t), s = sinf(0.5f * t);
    M2 U;
    U.m[0] = make_float2(c, -s); U.m[1] = make_float2(0.f, 0.f);
    U.m[2] = make_float2(0.f, 0.f); U.m[3] = make_float2(c, s);
    return U;
}
__device__ M2 m2_rx(float t) {
    float c = cosf(0.5f * t), s = sinf(0.5f * t);
    M2 U;
    U.m[0] = make_float2(c, 0.f);   U.m[1] = make_float2(0.f, -s);
    U.m[2] = make_float2(0.f, -s);  U.m[3] = make_float2(c, 0.f);
    return U;
}
__device__ M2 m2_x() {
    M2 U;
    U.m[0] = make_float2(0.f, 0.f); U.m[1] = make_float2(1.f, 0.f);
    U.m[2] = make_float2(1.f, 0.f); U.m[3] = make_float2(0.f, 0.f);
    return U;
}

__device__ M4 cnot_hl() {  // control = high bit
    M4 C = m4_zero();
    C.m[0 * 4 + 0] = make_float2(1.f, 0.f);
    C.m[1 * 4 + 1] = make_float2(1.f, 0.f);
    C.m[2 * 4 + 3] = make_float2(1.f, 0.f);
    C.m[3 * 4 + 2] = make_float2(1.f, 0.f);
    return C;
}
__device__ M4 cnot_lh() {  // control = low bit (in 2a+b indexing)
    M4 C = m4_zero();
    C.m[0 * 4 + 0] = make_float2(1.f, 0.f);
    C.m[3 * 4 + 1] = make_float2(1.f, 0.f);
    C.m[2 * 4 + 2] = make_float2(1.f, 0.f);
    C.m[1 * 4 + 3] = make_float2(1.f, 0.f);
    return C;
}
__device__ M4 crz4(float t) {
    float c = cosf(0.5f * t), s = sinf(0.5f * t);
    M4 C = m4_zero();
    C.m[0] = make_float2(1.f, 0.f);
    C.m[5] = make_float2(1.f, 0.f);
    C.m[10] = make_float2(c, -s);
    C.m[15] = make_float2(c, s);
    return C;
}
__device__ M4 crx4(float t) {
    float c = cosf(0.5f * t), s = sinf(0.5f * t);
    M4 C = m4_zero();
    C.m[0] = make_float2(1.f, 0.f);
    C.m[5] = make_float2(1.f, 0.f);
    C.m[10] = make_float2(c, 0.f);
    C.m[11] = make_float2(0.f, -s);
    C.m[14] = make_float2(0.f, -s);
    C.m[15] = make_float2(c, 0.f);
    return C;
}

__device__ M4 conv_mat(const float* w) {
    M4 M = kronA(m2_u3(w[0], w[1], w[2]));
    M = mul4(kronB(m2_u3(w[3], w[4], w[5])), M);
    M = mul4(cnot_hl(), M);
    M = mul4(kronA(m2_ry(w[6])), M);
    M = mul4(kronB(m2_rz(w[7])), M);
    M = mul4(cnot_lh(), M);
    M = mul4(kronA(m2_ry(w[8])), M);
    M = mul4(cnot_hl(), M);
    M = mul4(kronA(m2_u3(w[9], w[10], w[11])), M);
    M = mul4(kronB(m2_u3(w[12], w[13], w[14])), M);
    return M;
}
__device__ M4 pool_mat(const float* p) {
    M4 M = crz4(p[0]);
    M = mul4(kronA(m2_x()), M);
    M = mul4(crx4(p[1]), M);
    return M;
}

__device__ void emit(Gate* g, int n, int a, int b, const M4& M) {
    g[n].p1 = 9 - a;   // qubit a -> bit (9-a) of flat index; a is the "2" bit of the 4-index
    g[n].p2 = 9 - b;
    for (int i = 0; i < 16; i++) g[n].m[i] = M.m[i];
}

__global__ void build_gates(const float* wc1, const float* wc2,
                            const float* wp1, const float* wp2,
                            const float* wfc, Gate* g) {
    if (threadIdx.x != 0 || blockIdx.x != 0) return;
    int n = 0;
    // conv layer 1: even pairs, odd pairs, wraparound reusing row 7
    for (int i = 0; i < 10; i += 2) { emit(g, n++, i, i + 1, conv_mat(wc1 + 15 * i)); }
    for (int i = 1; i < 9; i += 2)  { emit(g, n++, i, i + 1, conv_mat(wc1 + 15 * i)); }
    emit(g, n++, 0, 9, conv_mat(wc1 + 15 * 7));
    // pool layer 1: (c=i+1, t=i)
    {
        int idx = 0;
        for (int i = 0; i < 10; i += 2) { emit(g, n++, i + 1, i, pool_mat(wp1 + 2 * idx)); idx++; }
    }
    // conv layer 2: (i, i+2)
    {
        int idx = 0;
        for (int i = 0; i < 8; i += 2) { emit(g, n++, i, i + 2, conv_mat(wc2 + 15 * idx)); idx++; }
    }
    // pool layer 2: (c=i+2, t=i), i = 0, 4
    emit(g, n++, 2, 0, pool_mat(wp2 + 0));
    emit(g, n++, 6, 4, pool_mat(wp2 + 2));
    // fc entanglers + RX
    emit(g, n++, 0, 4, cnot_hl());
    emit(g, n++, 2, 4, cnot_hl());
    emit(g, n++, 4, 0, cnot_hl());
    emit(g, n++, 0, 1, kronA(m2_rx(wfc[0])));
    emit(g, n++, 2, 3, kronA(m2_rx(wfc[1])));
    emit(g, n++, 4, 5, kronA(m2_rx(wfc[2])));
    // n == 27
}

// One block per input basis state t: simulate U|t> in LDS, write row t of B.
// B[t][s] = Re U[s][t], B[t][1024+s] = Im U[s][t].  B is [1024][2048] row-major.
__global__ __launch_bounds__(256) void build_U(const Gate* __restrict__ gates,
                                               float* __restrict__ B) {
    __shared__ float2 st[1024];
    const int t = blockIdx.x;
    for (int i = threadIdx.x; i < 1024; i += 256) st[i] = make_float2(0.f, 0.f);
    __syncthreads();
    if (threadIdx.x == 0) st[t] = make_float2(1.f, 0.f);
    __syncthreads();

    for (int g = 0; g < 27; g++) {
        const int p1 = gates[g].p1, p2 = gates[g].p2;
        float2 m[16];
        for (int i = 0; i < 16; i++) m[i] = gates[g].m[i];
        const int lo = min(p1, p2), hi = max(p1, p2);
        const int q = threadIdx.x;          // 256 quads, one per thread
        const int m1 = (1 << lo) - 1;
        int tt = (q & m1) | ((q & ~m1) << 1);
        const int m2 = (1 << hi) - 1;
        const int i0 = (tt & m2) | ((tt & ~m2) << 1);
        int idx[4];
        for (int ga = 0; ga < 2; ga++)
            for (int gb = 0; gb < 2; gb++)
                idx[2 * ga + gb] = i0 | (ga << p1) | (gb << p2);
        float2 v[4];
        for (int i = 0; i < 4; i++) v[i] = st[idx[i]];
        float2 nv[4];
        for (int i = 0; i < 4; i++) {
            float2 s = make_float2(0.f, 0.f);
            for (int j = 0; j < 4; j++) s = cadd(s, cmul(m[i * 4 + j], v[j]));
            nv[i] = s;
        }
        for (int i = 0; i < 4; i++) st[idx[i]] = nv[i];
        __syncthreads();
    }
    for (int s = threadIdx.x; s < 1024; s += 256) {
        B[(size_t)t * 2048 + s] = st[s].x;
        B[(size_t)t * 2048 + 1024 + s] = st[s].y;
    }
}

// Row sum of squares of X: nrm2[b] = ||x_b||^2.  One block per row.
__global__ __launch_bounds__(256) void row_norm2(const float* __restrict__ X,
                                                 float* __restrict__ nrm2) {
    const int b = blockIdx.x;
    const float4* xr = (const float4*)(X + (size_t)b * 1024);
    float4 v = xr[threadIdx.x];
    float s = v.x * v.x + v.y * v.y + v.z * v.z + v.w * v.w;
    for (int off = 32; off >= 1; off >>= 1) s += __shfl_xor(s, off, 64);
    __shared__ float ws[4];
    const int lane = threadIdx.x & 63, wid = threadIdx.x >> 6;
    if (lane == 0) ws[wid] = s;
    __syncthreads();
    if (threadIdx.x == 0) nrm2[b] = ws[0] + ws[1] + ws[2] + ws[3];
}

// Y = X @ B, fused epilogue: acc[b][k] += sum_n sign_k(n) * Y[b][n]^2
// Block tile 64(batch) x 64(n), 256 threads, 4x4 micro-tile, BK=16.
#define BM 64
#define BN 64
#define BK 16
__global__ __launch_bounds__(256) void gemm_qform(const float* __restrict__ X,
                                                  const float* __restrict__ Bmat,
                                                  float* __restrict__ acc) {
    __shared__ float As[BK][BM + 4];   // [k][m], padded stride 68 (16B-aligned, low conflict)
    __shared__ float Bs[BK][BN];       // [k][n]
    const int tid = threadIdx.x;
    const int tx = tid & 15, ty = tid >> 4;
    const int row0 = blockIdx.x * BM;
    const int col0 = blockIdx.y * BN;

    float accf[4][4];
    for (int i = 0; i < 4; i++)
        for (int j = 0; j < 4; j++) accf[i][j] = 0.f;

    const int ar = tid >> 2;            // 0..63 : batch row within tile
    const int ak = (tid & 3) * 4;       // 0,4,8,12
    const int bk = tid >> 4;            // 0..15 : k row
    const int bn = (tid & 15) * 4;      // 0..60

    for (int k0 = 0; k0 < 1024; k0 += BK) {
        float4 av = *(const float4*)&X[(size_t)(row0 + ar) * 1024 + k0 + ak];
        As[ak + 0][ar] = av.x;
        As[ak + 1][ar] = av.y;
        As[ak + 2][ar] = av.z;
        As[ak + 3][ar] = av.w;
        *(float4*)&Bs[bk][bn] = *(const float4*)&Bmat[(size_t)(k0 + bk) * 2048 + col0 + bn];
        __syncthreads();
#pragma unroll
        for (int k = 0; k < BK; k++) {
            float a[4], b[4];
            *(float4*)a = *(const float4*)&As[k][ty * 4];
            *(float4*)b = *(const float4*)&Bs[k][tx * 4];
#pragma unroll
            for (int i = 0; i < 4; i++)
#pragma unroll
                for (int j = 0; j < 4; j++) accf[i][j] = fmaf(a[i], b[j], accf[i][j]);
        }
        __syncthreads();
    }

    // epilogue: signed squares, reduce over the 16 tx lanes (contiguous in wave)
    float c0[4] = {0.f, 0.f, 0.f, 0.f}, c1[4] = {0.f, 0.f, 0.f, 0.f};
#pragma unroll
    for (int j = 0; j < 4; j++) {
        const int n = col0 + tx * 4 + j;
        const int s = n & 1023;                      // real/imag cols share sign
        const float s0 = ((s >> 9) & 1) ? -1.f : 1.f;  // qubit 0 = bit 9
        const float s1 = ((s >> 7) & 1) ? -1.f : 1.f;  // qubit 2 = bit 7
#pragma unroll
        for (int i = 0; i < 4; i++) {
            const float y2 = accf[i][j] * accf[i][j];
            c0[i] += s0 * y2;
            c1[i] += s1 * y2;
        }
    }
#pragma unroll
    for (int off = 1; off < 16; off <<= 1) {
#pragma unroll
        for (int i = 0; i < 4; i++) {
            c0[i] += __shfl_xor(c0[i], off, 64);
            c1[i] += __shfl_xor(c1[i], off, 64);
        }
    }
    if (tx == 0) {
#pragma unroll
        for (int i = 0; i < 4; i++) {
            const int row = row0 + ty * 4 + i;
            atomicAdd(&acc[row * 2 + 0], c0[i]);
            atomicAdd(&acc[row * 2 + 1], c1[i]);
        }
    }
}

__global__ __launch_bounds__(256) void finalize(const float* __restrict__ acc,
                                                const float* __restrict__ nrm2,
                                                float* __restrict__ out) {
    const int i = blockIdx.x * 256 + threadIdx.x;   // 32768
    out[i] = acc[i] / nrm2[i >> 1];
}

extern "C" void kernel_launch(void* const* d_in, const int* in_sizes, int n_in,
                              void* d_out, int out_size, void* d_ws, size_t ws_size,
                              hipStream_t stream) {
    const float* x   = (const float*)d_in[0];   // 16384 x 1024
    const float* wc1 = (const float*)d_in[1];   // 10 x 15
    const float* wc2 = (const float*)d_in[2];   // 4 x 15
    const float* wp1 = (const float*)d_in[3];   // 5 x 2
    const float* wp2 = (const float*)d_in[4];   // 2 x 2
    const float* wfc = (const float*)d_in[5];   // 3
    float* out = (float*)d_out;                 // 16384 x 2

    uintptr_t w = (uintptr_t)d_ws;
    Gate* gates  = (Gate*)w;                                   // 27*136 B
    float* Bmat  = (float*)(w + 4096);                         // 8 MB
    float* nrm2  = (float*)(w + 4096 + 8388608);               // 64 KB
    float* acc   = (float*)(w + 4096 + 8388608 + 65536);       // 128 KB

    hipMemsetAsync(acc, 0, 32768 * sizeof(float), stream);
    build_gates<<<1, 64, 0, stream>>>(wc1, wc2, wp1, wp2, wfc, gates);
    row_norm2<<<16384, 256, 0, stream>>>(x, nrm2);
    build_U<<<1024, 256, 0, stream>>>(gates, Bmat);
    gemm_qform<<<dim3(16384 / BM, 2048 / BN), 256, 0, stream>>>(x, Bmat, acc);
    finalize<<<32768 / 256, 256, 0, stream>>>(acc, nrm2, out);
}

// Round 2
// 274.468 us; speedup vs baseline: 4.6326x; 4.6326x over previous
//
#include <hip/hip_runtime.h>

// ---------------------------------------------------------------------------
// QCNN classifier: whole circuit == fixed 1024x1024 unitary U(weights).
// out[b,k] = sum_s sign_k(s) |(U x_b)_s|^2 / ||x_b||^2
// R2: f16 MFMA GEMM (m97-style 128x128 tile, global_load_lds w=16, LDS
// XOR-swizzle -> conflict-free ds_read_b128), fused signed-square epilogue
// to per-block partials; build_gates parallelized (1 thread/gate).
// ---------------------------------------------------------------------------

typedef _Float16 f16;
typedef f16 f16x8 __attribute__((ext_vector_type(8)));
typedef f16 f16x4 __attribute__((ext_vector_type(4)));
typedef float f32x4 __attribute__((ext_vector_type(4)));

struct Gate { int p1, p2; float2 m[16]; };   // p1 = bitpos of high gate index bit

__device__ inline float2 cmul(float2 a, float2 b) {
    return make_float2(a.x * b.x - a.y * b.y, a.x * b.y + a.y * b.x);
}
__device__ inline float2 cadd(float2 a, float2 b) {
    return make_float2(a.x + b.x, a.y + b.y);
}

struct M2 { float2 m[4]; };
struct M4 { float2 m[16]; };

__device__ M4 m4_zero() {
    M4 C;
    for (int i = 0; i < 16; i++) C.m[i] = make_float2(0.f, 0.f);
    return C;
}

__device__ M4 mul4(const M4& A, const M4& B) {
    M4 C;
    for (int i = 0; i < 4; i++)
        for (int j = 0; j < 4; j++) {
            float2 s = make_float2(0.f, 0.f);
            for (int k = 0; k < 4; k++) s = cadd(s, cmul(A.m[i * 4 + k], B.m[k * 4 + j]));
            C.m[i * 4 + j] = s;
        }
    return C;
}

// U acting on high qubit of (a,b) pair: U (x) I
__device__ M4 kronA(const M2& U) {
    M4 C = m4_zero();
    for (int a2 = 0; a2 < 2; a2++)
        for (int a = 0; a < 2; a++)
            for (int b = 0; b < 2; b++)
                C.m[(2 * a2 + b) * 4 + (2 * a + b)] = U.m[a2 * 2 + a];
    return C;
}
// U acting on low qubit: I (x) U
__device__ M4 kronB(const M2& U) {
    M4 C = m4_zero();
    for (int a = 0; a < 2; a++)
        for (int b2 = 0; b2 < 2; b2++)
            for (int b = 0; b < 2; b++)
                C.m[(2 * a + b2) * 4 + (2 * a + b)] = U.m[b2 * 2 + b];
    return C;
}

__device__ M2 m2_u3(float t, float p, float d) {
    float c = cosf(0.5f * t), s = sinf(0.5f * t);
    float2 ep = make_float2(cosf(p), sinf(p));
    float2 ed = make_float2(cosf(d), sinf(d));
    M2 U;
    U.m[0] = make_float2(c, 0.f);
    U.m[1] = make_float2(-ed.x * s, -ed.y * s);
    U.m[2] = make_float2(ep.x * s, ep.y * s);
    float2 epd = cmul(ep, ed);
    U.m[3] = make_float2(epd.x * c, epd.y * c);
    return U;
}
__device__ M2 m2_ry(float t) {
    float c = cosf(0.5f * t), s = sinf(0.5f * t);
    M2 U;
    U.m[0] = make_float2(c, 0.f);  U.m[1] = make_float2(-s, 0.f);
    U.m[2] = make_float2(s, 0.f);  U.m[3] = make_float2(c, 0.f);
    return U;
}
__device__ M2 m2_rz(float t) {
    float c = cosf(0.5f * t), s = sinf(0.5f * t);
    M2 U;
    U.m[0] = make_float2(c, -s); U.m[1] = make_float2(0.f, 0.f);
    U.m[2] = make_float2(0.f, 0.f); U.m[3] = make_float2(c, s);
    return U;
}
__device__ M2 m2_rx(float t) {
    float c = cosf(0.5f * t), s = sinf(0.5f * t);
    M2 U;
    U.m[0] = make_float2(c, 0.f);   U.m[1] = make_float2(0.f, -s);
    U.m[2] = make_float2(0.f, -s);  U.m[3] = make_float2(c, 0.f);
    return U;
}
__device__ M2 m2_x() {
    M2 U;
    U.m[0] = make_float2(0.f, 0.f); U.m[1] = make_float2(1.f, 0.f);
    U.m[2] = make_float2(1.f, 0.f); U.m[3] = make_float2(0.f, 0.f);
    return U;
}

__device__ M4 cnot_hl() {  // control = high bit
    M4 C = m4_zero();
    C.m[0 * 4 + 0] = make_float2(1.f, 0.f);
    C.m[1 * 4 + 1] = make_float2(1.f, 0.f);
    C.m[2 * 4 + 3] = make_float2(1.f, 0.f);
    C.m[3 * 4 + 2] = make_float2(1.f, 0.f);
    return C;
}
__device__ M4 cnot_lh() {  // control = low bit
    M4 C = m4_zero();
    C.m[0 * 4 + 0] = make_float2(1.f, 0.f);
    C.m[3 * 4 + 1] = make_float2(1.f, 0.f);
    C.m[2 * 4 + 2] = make_float2(1.f, 0.f);
    C.m[1 * 4 + 3] = make_float2(1.f, 0.f);
    return C;
}
__device__ M4 crz4(float t) {
    float c = cosf(0.5f * t), s = sinf(0.5f * t);
    M4 C = m4_zero();
    C.m[0] = make_float2(1.f, 0.f);
    C.m[5] = make_float2(1.f, 0.f);
    C.m[10] = make_float2(c, -s);
    C.m[15] = make_float2(c, s);
    return C;
}
__device__ M4 crx4(float t) {
    float c = cosf(0.5f * t), s = sinf(0.5f * t);
    M4 C = m4_zero();
    C.m[0] = make_float2(1.f, 0.f);
    C.m[5] = make_float2(1.f, 0.f);
    C.m[10] = make_float2(c, 0.f);
    C.m[11] = make_float2(0.f, -s);
    C.m[14] = make_float2(0.f, -s);
    C.m[15] = make_float2(c, 0.f);
    return C;
}

__device__ M4 conv_mat(const float* w) {
    M4 M = kronA(m2_u3(w[0], w[1], w[2]));
    M = mul4(kronB(m2_u3(w[3], w[4], w[5])), M);
    M = mul4(cnot_hl(), M);
    M = mul4(kronA(m2_ry(w[6])), M);
    M = mul4(kronB(m2_rz(w[7])), M);
    M = mul4(cnot_lh(), M);
    M = mul4(kronA(m2_ry(w[8])), M);
    M = mul4(cnot_hl(), M);
    M = mul4(kronA(m2_u3(w[9], w[10], w[11])), M);
    M = mul4(kronB(m2_u3(w[12], w[13], w[14])), M);
    return M;
}
__device__ M4 pool_mat(const float* p) {
    M4 M = crz4(p[0]);
    M = mul4(kronA(m2_x()), M);
    M = mul4(crx4(p[1]), M);
    return M;
}

__device__ void emit(Gate* g, int n, int a, int b, const M4& M) {
    g[n].p1 = 9 - a;
    g[n].p2 = 9 - b;
    for (int i = 0; i < 16; i++) g[n].m[i] = M.m[i];
}

// One thread per gate (27 gates) — was serial on one thread in R1 (~hundreds of us).
__global__ void build_gates(const float* wc1, const float* wc2,
                            const float* wp1, const float* wp2,
                            const float* wfc, Gate* g) {
    const int n = threadIdx.x;
    if (blockIdx.x != 0 || n >= 27) return;
    int a, b; M4 M;
    if (n < 5)        { int i = 2*n;           a = i;   b = i+1; M = conv_mat(wc1 + 15*i); }
    else if (n < 9)   { int i = 2*(n-5)+1;     a = i;   b = i+1; M = conv_mat(wc1 + 15*i); }
    else if (n == 9)  { a = 0; b = 9;          M = conv_mat(wc1 + 105); }
    else if (n < 15)  { int idx = n-10, i = 2*idx; a = i+1; b = i; M = pool_mat(wp1 + 2*idx); }
    else if (n < 19)  { int idx = n-15, i = 2*idx; a = i; b = i+2; M = conv_mat(wc2 + 15*idx); }
    else if (n == 19) { a = 2; b = 0;          M = pool_mat(wp2 + 0); }
    else if (n == 20) { a = 6; b = 4;          M = pool_mat(wp2 + 2); }
    else if (n == 21) { a = 0; b = 4;          M = cnot_hl(); }
    else if (n == 22) { a = 2; b = 4;          M = cnot_hl(); }
    else if (n == 23) { a = 4; b = 0;          M = cnot_hl(); }
    else if (n == 24) { a = 0; b = 1;          M = kronA(m2_rx(wfc[0])); }
    else if (n == 25) { a = 2; b = 3;          M = kronA(m2_rx(wfc[1])); }
    else              { a = 4; b = 5;          M = kronA(m2_rx(wfc[2])); }
    emit(g, n, a, b, M);
}

// One block per input basis state t: simulate U|t> in LDS, write row t of B.
// B[t][s] = Re U[s][t], B[t][1024+s] = Im U[s][t].  B is [1024][2048] row-major.
__global__ __launch_bounds__(256) void build_U(const Gate* __restrict__ gates,
                                               float* __restrict__ B) {
    __shared__ float2 st[1024];
    const int t = blockIdx.x;
    for (int i = threadIdx.x; i < 1024; i += 256) st[i] = make_float2(0.f, 0.f);
    __syncthreads();
    if (threadIdx.x == 0) st[t] = make_float2(1.f, 0.f);
    __syncthreads();

    for (int g = 0; g < 27; g++) {
        const int p1 = gates[g].p1, p2 = gates[g].p2;
        float2 m[16];
        for (int i = 0; i < 16; i++) m[i] = gates[g].m[i];
        const int lo = min(p1, p2), hi = max(p1, p2);
        const int q = threadIdx.x;
        const int m1 = (1 << lo) - 1;
        int tt = (q & m1) | ((q & ~m1) << 1);
        const int m2 = (1 << hi) - 1;
        const int i0 = (tt & m2) | ((tt & ~m2) << 1);
        int idx[4];
        for (int ga = 0; ga < 2; ga++)
            for (int gb = 0; gb < 2; gb++)
                idx[2 * ga + gb] = i0 | (ga << p1) | (gb << p2);
        float2 v[4];
        for (int i = 0; i < 4; i++) v[i] = st[idx[i]];
        float2 nv[4];
        for (int i = 0; i < 4; i++) {
            float2 s = make_float2(0.f, 0.f);
            for (int j = 0; j < 4; j++) s = cadd(s, cmul(m[i * 4 + j], v[j]));
            nv[i] = s;
        }
        for (int i = 0; i < 4; i++) st[idx[i]] = nv[i];
        __syncthreads();
    }
    for (int s = threadIdx.x; s < 1024; s += 256) {
        B[(size_t)t * 2048 + s] = st[s].x;
        B[(size_t)t * 2048 + 1024 + s] = st[s].y;
    }
}

// B fp32 [1024 k][2048 n]  ->  BTh fp16 [2048 n][1024 k], LDS tiled transpose.
__global__ __launch_bounds__(256) void transpose_b(const float* __restrict__ B,
                                                   f16* __restrict__ BTh) {
    __shared__ float t[32][33];
    const int n0 = blockIdx.x * 32, k0 = blockIdx.y * 32;
    const int c = threadIdx.x & 31, r = threadIdx.x >> 5;   // r = 0..7
#pragma unroll
    for (int i = 0; i < 4; i++) {
        int k = r + i * 8;
        t[k][c] = B[(size_t)(k0 + k) * 2048 + n0 + c];
    }
    __syncthreads();
#pragma unroll
    for (int i = 0; i < 4; i++) {
        int n = r + i * 8;
        BTh[(size_t)(n0 + n) * 1024 + k0 + c] = (f16)t[c][n];
    }
}

// Row norms + fp32->fp16 conversion of X (read X once).
__global__ __launch_bounds__(256) void norm_conv(const float* __restrict__ X,
                                                 float* __restrict__ nrm2,
                                                 f16* __restrict__ Xh) {
    const int b = blockIdx.x;
    float4 v = ((const float4*)(X + (size_t)b * 1024))[threadIdx.x];
    f16x4 h;
    h[0] = (f16)v.x; h[1] = (f16)v.y; h[2] = (f16)v.z; h[3] = (f16)v.w;
    *(f16x4*)(Xh + (size_t)b * 1024 + threadIdx.x * 4) = h;
    float s = v.x * v.x + v.y * v.y + v.z * v.z + v.w * v.w;
    for (int off = 32; off >= 1; off >>= 1) s += __shfl_xor(s, off, 64);
    __shared__ float ws2[4];
    const int lane = threadIdx.x & 63, wid = threadIdx.x >> 6;
    if (lane == 0) ws2[wid] = s;
    __syncthreads();
    if (threadIdx.x == 0) nrm2[b] = ws2[0] + ws2[1] + ws2[2] + ws2[3];
}

__device__ __forceinline__ void glds16(const void* g, void* l) {
    __builtin_amdgcn_global_load_lds(
        (const __attribute__((address_space(1))) void*)g,
        (__attribute__((address_space(3))) void*)l, 16, 0, 0);
}

// Y = Xh @ BTh^T fused with signed-square reduction.
// A: 16384x1024 f16 row-major. Bt: 2048x1024 f16 row-major (N x K).
// 128x128 tile, BK=32, 4 waves, each wave 64x64 via 4x4 of 16x16x32 MFMA.
// LDS tiles [row][k] with 16B-chunk XOR swizzle: phys_chunk = kc ^ ((row>>1)&3)
// -> global_load_lds stays lane-contiguous AND frag ds_read_b128 conflict-free.
// partial[by][row][k] = per-block signed-square sums over its 128 cols.
__global__ __launch_bounds__(256) void gemm_mfma(const f16* __restrict__ A,
                                                 const f16* __restrict__ Bt,
                                                 float* __restrict__ partial) {
    __shared__ char Ash[8192];
    __shared__ char Bsh[8192];
    __shared__ float pLDS[128][2][2];
    const int tid = threadIdx.x;
    const int l = tid & 63, w = tid >> 6;
    const int wr = w >> 1, wc = w & 1;
    const int row0 = blockIdx.x * 128, col0 = blockIdx.y * 128;

    // staging: wave w stages chunks 2w, 2w+1 of each tile (16 rows x 32k per chunk)
    // lane l -> phys LDS offset chunk*1024 + l*16 == row (chunk*16 + l>>2), phys kc (l&3)
    // logical kc = (l&3) ^ ((row>>1)&3) = (l&3) ^ ((l>>3)&3)   (chunk*16 drops out)
    const int mrow = l >> 2;
    const int kc = (l & 3) ^ ((l >> 3) & 3);
    const f16* aS0 = A  + (size_t)(row0 + 32 * w + mrow) * 1024 + kc * 8;
    const f16* aS1 = aS0 + 16 * 1024;
    const f16* bS0 = Bt + (size_t)(col0 + 32 * w + mrow) * 1024 + kc * 8;
    const f16* bS1 = bS0 + 16 * 1024;
    char* aD0 = Ash + 2048 * w;
    char* aD1 = aD0 + 1024;
    char* bD0 = Bsh + 2048 * w;
    char* bD1 = bD0 + 1024;

    // fragment ds_read offsets (k-invariant): A[m = lane&15][k = (lane>>4)*8 + j]
    int aOff[4], bOff[4];
#pragma unroll
    for (int i = 0; i < 4; i++) {
        int m = wr * 64 + i * 16 + (l & 15);
        aOff[i] = m * 64 + (((l >> 4) ^ ((m >> 1) & 3)) << 4);
        int n = wc * 64 + i * 16 + (l & 15);
        bOff[i] = n * 64 + (((l >> 4) ^ ((n >> 1) & 3)) << 4);
    }

    f32x4 acc[4][4];
    const f32x4 z = {0.f, 0.f, 0.f, 0.f};
#pragma unroll
    for (int i = 0; i < 4; i++)
#pragma unroll
        for (int j = 0; j < 4; j++) acc[i][j] = z;

    for (int k0 = 0; k0 < 1024; k0 += 32) {
        glds16(aS0 + k0, aD0);
        glds16(aS1 + k0, aD1);
        glds16(bS0 + k0, bD0);
        glds16(bS1 + k0, bD1);
        __syncthreads();
        f16x8 af[4], bf[4];
#pragma unroll
        for (int i = 0; i < 4; i++) {
            af[i] = *(const f16x8*)(Ash + aOff[i]);
            bf[i] = *(const f16x8*)(Bsh + bOff[i]);
        }
#pragma unroll
        for (int mi = 0; mi < 4; mi++)
#pragma unroll
            for (int ni = 0; ni < 4; ni++)
                acc[mi][ni] = __builtin_amdgcn_mfma_f32_16x16x32_f16(
                    af[mi], bf[ni], acc[mi][ni], 0, 0, 0);
        __syncthreads();
    }

    // fused epilogue: signed squares, reduce cols
    float c0[4][4], c1[4][4];   // [mi][reg-row]
#pragma unroll
    for (int mi = 0; mi < 4; mi++)
#pragma unroll
        for (int rr = 0; rr < 4; rr++) { c0[mi][rr] = 0.f; c1[mi][rr] = 0.f; }
#pragma unroll
    for (int ni = 0; ni < 4; ni++) {
        const int n_glob = col0 + wc * 64 + ni * 16 + (l & 15);
        const int s = n_glob & 1023;                    // real/imag cols share sign
        const float s0 = ((s >> 9) & 1) ? -1.f : 1.f;   // qubit 0 = bit 9
        const float s1 = ((s >> 7) & 1) ? -1.f : 1.f;   // qubit 2 = bit 7
#pragma unroll
        for (int mi = 0; mi < 4; mi++)
#pragma unroll
            for (int rr = 0; rr < 4; rr++) {
                const float y = acc[mi][ni][rr];
                const float y2 = y * y;
                c0[mi][rr] += s0 * y2;
                c1[mi][rr] += s1 * y2;
            }
    }
    // reduce over the 16 col-lanes (low 4 lane bits)
#pragma unroll
    for (int off = 1; off < 16; off <<= 1)
#pragma unroll
        for (int mi = 0; mi < 4; mi++)
#pragma unroll
            for (int rr = 0; rr < 4; rr++) {
                c0[mi][rr] += __shfl_xor(c0[mi][rr], off, 64);
                c1[mi][rr] += __shfl_xor(c1[mi][rr], off, 64);
            }
    if ((l & 15) == 0) {
        const int q = l >> 4;
#pragma unroll
        for (int mi = 0; mi < 4; mi++)
#pragma unroll
            for (int rr = 0; rr < 4; rr++) {
                const int r = wr * 64 + mi * 16 + q * 4 + rr;
                pLDS[r][wc][0] = c0[mi][rr];
                pLDS[r][wc][1] = c1[mi][rr];
            }
    }
    __syncthreads();
    {
        const int r = tid >> 1, k = tid & 1;
        const float v = pLDS[r][0][k] + pLDS[r][1][k];
        partial[((size_t)blockIdx.y * 16384 + row0 + r) * 2 + k] = v;
    }
}

__global__ __launch_bounds__(256) void finalize(const float* __restrict__ partial,
                                                const float* __restrict__ nrm2,
                                                float* __restrict__ out) {
    const int i = blockIdx.x * 256 + threadIdx.x;   // 32768
    const int b = i >> 1, k = i & 1;
    float s = 0.f;
#pragma unroll
    for (int ny = 0; ny < 16; ny++) s += partial[((size_t)ny * 16384 + b) * 2 + k];
    out[i] = s / nrm2[b];
}

extern "C" void kernel_launch(void* const* d_in, const int* in_sizes, int n_in,
                              void* d_out, int out_size, void* d_ws, size_t ws_size,
                              hipStream_t stream) {
    const float* x   = (const float*)d_in[0];   // 16384 x 1024
    const float* wc1 = (const float*)d_in[1];   // 10 x 15
    const float* wc2 = (const float*)d_in[2];   // 4 x 15
    const float* wp1 = (const float*)d_in[3];   // 5 x 2
    const float* wp2 = (const float*)d_in[4];   // 2 x 2
    const float* wfc = (const float*)d_in[5];   // 3
    float* out = (float*)d_out;                 // 16384 x 2

    uintptr_t wsp = (uintptr_t)d_ws;
    Gate*  gates   = (Gate*)wsp;                                  // 4 KB
    float* Bmat    = (float*)(wsp + 4096);                        // 8 MB
    f16*   BTh     = (f16*)(wsp + 4096 + (8u << 20));             // 4 MB
    f16*   Xh      = (f16*)(wsp + 4096 + (12u << 20));            // 32 MB
    float* nrm2    = (float*)(wsp + 4096 + (44u << 20));          // 64 KB
    float* partial = (float*)(wsp + 4096 + (44u << 20) + 65536);  // 2 MB

    build_gates<<<1, 32, 0, stream>>>(wc1, wc2, wp1, wp2, wfc, gates);
    norm_conv<<<16384, 256, 0, stream>>>(x, nrm2, Xh);
    build_U<<<1024, 256, 0, stream>>>(gates, Bmat);
    transpose_b<<<dim3(64, 32), 256, 0, stream>>>(Bmat, BTh);
    gemm_mfma<<<dim3(128, 16), 256, 0, stream>>>(Xh, BTh, partial);
    finalize<<<128, 256, 0, stream>>>(partial, nrm2, out);
}